// Round 11
// baseline (274.950 us; speedup 1.0000x reference)
//
#include <hip/hip_runtime.h>
#include <hip/hip_fp16.h>

// DeepNovo intensity-window gather, round 14: WAVE-CONTIGUOUS STORE WINDOWS.
// Ledger: R8/R9/R10/R13 all ~107us (5 nulls). R12 probes: gather-only 19us
// VALU-100%; store-only <=60.7us/pass (>=4.5 TB/s) -- pure store path FAST.
// Full kernel stores: 2.55 TB/s. Little's law: low equilibrium means the
// DRAIN is slow for our stream. Named mechanism: temporal write dispersion.
// Per-wave stores stride 7.6MB; 512 decorrelated waves -> instantaneous HBM
// write stream = 1KB granules scattered over 272MB -> row-buffer misses ->
// ~2.5 TB/s. Fill/probe stream compactly -> 6.5. Explains every null (nt,
// occupancy, vmcnt, phasing never changed WHERE bytes land in time).
// R14: remap f = (block*16+wave)*2304 + k*64 + lane -> each wave writes a
// CONTIGUOUS 36KB window (36 sequential 1KB stores); each CU streams
// ~576KB sequentially. Cost: col varies per iter -> incremental (row,col)
// walk (+3 VALU, branchless wrap) + per-col constants from an LDS uint2
// table (stride-8, conflict-free). LDS 64,752B <= 64KB. Arithmetic per
// (row,col) bit-identical to R10 (absmax 0.0039 from fp16 spectrum).
// Predict: drain 2.55 -> >=5.5 TB/s, kernel ~55-75us, dur ~225-250.
// Null (~273) kills the mechanism -> next round: x4-repeat for undilated
// full-kernel counters.

#define MASS_H2O 18.01056f
#define MASS_NH3 17.02655f

typedef float floatx4 __attribute__((ext_vector_type(4)));

constexpr int MAX_MZ = 30000;
constexpr int WIN = 10;
constexpr int CPR = 520;                  // float4 chunks per batch row
constexpr int BLOCK = 1024;               // 16 waves
constexpr int KIT = 36;                   // stores per wave
constexpr int WAVE_WIN = KIT * 64;        // 2304 chunks per wave
constexpr int BLK_WIN = (BLOCK / 64) * WAVE_WIN;   // 36864 chunks per block
constexpr int SPAD = 30004;               // spectrum halfwords + pad
constexpr int NROW = 73;                  // rows spanned by a block (<=72)+1

__global__ __launch_bounds__(BLOCK) void intensity_kernel(
    const float* __restrict__ spectrum,
    const float* __restrict__ pepmass,
    const float* __restrict__ prefix_mass,
    const float* __restrict__ masses,
    const int*   __restrict__ dir_p,
    float* __restrict__ out,
    int batch)
{
    __shared__ __half  sspec[SPAD];       // 60,008 B
    __shared__ uint2   stbl[CPR];         //  4,160 B  per-col constants
    __shared__ float2  spmf[NROW];        //    584 B  (pm, pf) per row

    const unsigned fb      = (unsigned)blockIdx.x * (unsigned)BLK_WIN;
    const unsigned totalF  = (unsigned)batch * (unsigned)CPR;
    const unsigned rowBase = fb / (unsigned)CPR;

    // ---- stage spectrum fp32 -> fp16 into LDS ----
    {
        const float2* sp2 = reinterpret_cast<const float2*>(spectrum);
        __half2* dst = reinterpret_cast<__half2*>(sspec);
#pragma unroll 4
        for (int i = threadIdx.x; i < MAX_MZ / 2; i += BLOCK) {
            float2 t = sp2[i];
            dst[i] = __floats2half2_rn(t.x, t.y);
        }
        if (threadIdx.x < (SPAD - MAX_MZ) / 2)
            dst[MAX_MZ / 2 + threadIdx.x] = __floats2half2_rn(0.f, 0.f);
    }
    // ---- stage this block's pm/pf rows ----
    if (threadIdx.x < NROW) {
        int r = (int)rowBase + (int)threadIdx.x;
        float2 val = {0.0f, 0.0f};
        if (r < batch) { val.x = pepmass[r]; val.y = prefix_mass[r]; }
        spmf[threadIdx.x] = val;
    }
    // ---- build per-col constant table (bit-exact decode, done once) ----
    if (threadIdx.x < CPR) {
        const int c = threadIdx.x;
        const int dir = dir_p[0];
        int v = c / 20, q = c - 20 * v;
        int e0 = 4 * q;
        int ionA = e0 / 10,       wp0 = e0 - 10 * ionA;
        int ionB = (e0 + 2) / 10, wp1 = (e0 + 2) - 10 * ionB;
        int kA = ionA & 3, kB = ionB & 3;
        unsigned fl = (unsigned)wp0 | ((unsigned)wp1 << 4);
        if ((ionA >= 4) ^ (dir != 0)) fl |= 1u << 8;    // suA: base = u
        if ((ionB >= 4) ^ (dir != 0)) fl |= 1u << 9;    // suB
        if (kA == 3) fl |= 1u << 10;                    // mjA = 5 (else 10)
        if (kB == 3) fl |= 1u << 11;                    // mjB
        if (v > 2)   fl |= 1u << 12;                    // label mask
        if (kA == 1) fl |= 1u << 16;                    // ajA = -H2O
        if (kA == 2) fl |= 1u << 17;                    // ajA = -NH3
        if (kB == 1) fl |= 1u << 18;
        if (kB == 2) fl |= 1u << 19;
        uint2 e;
        e.x = __float_as_uint(masses[v]);
        e.y = fl;
        stbl[c] = e;
    }
    __syncthreads();

    const int wv   = (int)threadIdx.x >> 6;
    const int lane = (int)threadIdx.x & 63;
    unsigned f   = fb + (unsigned)wv * (unsigned)WAVE_WIN + (unsigned)lane;
    unsigned row = f / (unsigned)CPR;                  // one div, then walk
    unsigned col = f - row * (unsigned)CPR;
    unsigned rel = row - rowBase;                      // 0..71, always staged

    const uint32_t* spec32 = reinterpret_cast<const uint32_t*>(sspec);
    floatx4* out4 = reinterpret_cast<floatx4*>(out);

#pragma unroll 4
    for (int k = 0; k < KIT; ++k) {
        float2 pp = spmf[rel];                         // <=2 addrs/wave
        uint2  tb = stbl[col];                         // stride-8: conflict-free
        float  ms = __uint_as_float(tb.x);
        unsigned fl = tb.y;
        float t = pp.y + ms;                           // exact ref arithmetic
        float u = pp.x - t;

        // slot A
        float baseA = (fl & (1u << 8)) ? u : t;
        float ajA = (fl & (1u << 16)) ? -MASS_H2O
                  : (fl & (1u << 17)) ? -MASS_NH3 : 0.0f;
        float mjA = (fl & (1u << 10)) ? 5.0f : 10.0f;  // mul*10, bit-exact
        float fA = (baseA + ajA) * mjA;
        int idxA = (int)rintf(fA) - (WIN / 2);
        bool vA = (unsigned)idxA <= (unsigned)(MAX_MZ - WIN);
        int safeA = vA ? idxA : 0;
        // slot B
        float baseB = (fl & (1u << 9)) ? u : t;
        float ajB = (fl & (1u << 18)) ? -MASS_H2O
                  : (fl & (1u << 19)) ? -MASS_NH3 : 0.0f;
        float mjB = (fl & (1u << 11)) ? 5.0f : 10.0f;
        float fB = (baseB + ajB) * mjB;
        int idxB = (int)rintf(fB) - (WIN / 2);
        bool vB = (unsigned)idxB <= (unsigned)(MAX_MZ - WIN);
        int safeB = vB ? idxB : 0;

        bool lmb = (fl & (1u << 12)) != 0;
        float okA = (vA && lmb) ? 1.0f : 0.0f;
        float okB = (vB && lmb) ? 1.0f : 0.0f;

        // pair gathers: 2 consecutive halfwords via 2 aligned dwords each
        int h0 = safeA + (int)(fl & 15u);
        int h1 = safeB + (int)((fl >> 4) & 15u);
        int dw0 = h0 >> 1, dw1 = h1 >> 1;
        uint32_t a0 = spec32[dw0], a1 = spec32[dw0 + 1];   // ds_read2_b32
        uint32_t b0 = spec32[dw1], b1 = spec32[dw1 + 1];
        uint32_t r0 = (uint32_t)(((((uint64_t)a1) << 32) | a0) >> ((h0 & 1) << 4));
        uint32_t r1 = (uint32_t)(((((uint64_t)b1) << 32) | b0) >> ((h1 & 1) << 4));
        __half2 hv0 = *reinterpret_cast<__half2*>(&r0);
        __half2 hv1 = *reinterpret_cast<__half2*>(&r1);

        floatx4 r;
        r.x = __low2float(hv0)  * okA;
        r.y = __high2float(hv0) * okA;
        r.z = __low2float(hv1)  * okB;
        r.w = __high2float(hv1) * okB;
        if (f < totalF)
            out4[(size_t)f] = r;                       // sequential 1KB lines

        // incremental (f, col, rel) walk: +64 chunks, <=1 col wrap per iter
        f += 64u;
        unsigned nc = col + 64u;
        unsigned wrap = (nc >= (unsigned)CPR) ? 1u : 0u;
        col = nc - wrap * (unsigned)CPR;
        rel += wrap;
    }
}

extern "C" void kernel_launch(void* const* d_in, const int* in_sizes, int n_in,
                              void* d_out, int out_size, void* d_ws, size_t ws_size,
                              hipStream_t stream) {
    const float* spectrum    = (const float*)d_in[0];
    const float* pepmass     = (const float*)d_in[1];
    const float* prefix_mass = (const float*)d_in[2];
    const float* masses      = (const float*)d_in[3];
    const int*   direction   = (const int*)d_in[4];
    float* out = (float*)d_out;

    int batch = in_sizes[1];                           // 32768
    long long totalF = (long long)batch * CPR;         // 17,039,360
    int grid = (int)((totalF + BLK_WIN - 1) / BLK_WIN);// 463
    intensity_kernel<<<grid, BLOCK, 0, stream>>>(
        spectrum, pepmass, prefix_mass, masses, direction, out, batch);
}